// Round 1
// baseline (1190.912 us; speedup 1.0000x reference)
//
#include <hip/hip_runtime.h>
#include <math.h>

// Problem constants: B=16, C=512, H=W=64, N=H*W=4096
#define CCH    512
#define NTOK   4096
#define NBATCH 16

// ---------------------------------------------------------------------------
// K1: energy[b] = q[b] (C x N) * kv[b]^T  -> C x C   (NT GEMM, fp32)
// tile 128x128, k-chunk 32, 256 threads (16x16), 8x8 per thread.
// LDS stored transposed As[k][row] (pad 132 keeps float4 alignment + spreads banks)
// ---------------------------------------------------------------------------
__global__ __launch_bounds__(256)
void energy_kernel(const float* __restrict__ q, const float* __restrict__ kv,
                   float* __restrict__ E) {
    __shared__ float As[32][132];
    __shared__ float Bs[32][132];
    const int b  = blockIdx.z;
    const int c0 = blockIdx.y * 128;
    const int d0 = blockIdx.x * 128;
    const float* Abase = q  + (size_t)b * CCH * NTOK;
    const float* Bbase = kv + (size_t)b * CCH * NTOK;
    const int tid  = threadIdx.x;
    const int tx   = tid & 15, ty = tid >> 4;
    const int lrow = tid >> 1;          // 0..127: tile row this thread stages
    const int lk0  = (tid & 1) * 16;    // k offset 0 / 16

    const float* ga = Abase + (size_t)(c0 + lrow) * NTOK + lk0;
    const float* gb = Bbase + (size_t)(d0 + lrow) * NTOK + lk0;

    float acc[8][8];
#pragma unroll
    for (int i = 0; i < 8; ++i)
#pragma unroll
        for (int j = 0; j < 8; ++j) acc[i][j] = 0.f;

    float4 pa[4], pb[4];
#pragma unroll
    for (int i = 0; i < 4; ++i) {
        pa[i] = ((const float4*)ga)[i];
        pb[i] = ((const float4*)gb)[i];
    }

    for (int k0 = 0; k0 < NTOK; k0 += 32) {
        __syncthreads();
#pragma unroll
        for (int i = 0; i < 4; ++i) {
            const int kb = lk0 + i * 4;
            As[kb+0][lrow] = pa[i].x; As[kb+1][lrow] = pa[i].y;
            As[kb+2][lrow] = pa[i].z; As[kb+3][lrow] = pa[i].w;
            Bs[kb+0][lrow] = pb[i].x; Bs[kb+1][lrow] = pb[i].y;
            Bs[kb+2][lrow] = pb[i].z; Bs[kb+3][lrow] = pb[i].w;
        }
        __syncthreads();
        if (k0 + 32 < NTOK) {   // prefetch next chunk while computing this one
            const float* ga2 = ga + (k0 + 32);
            const float* gb2 = gb + (k0 + 32);
#pragma unroll
            for (int i = 0; i < 4; ++i) {
                pa[i] = ((const float4*)ga2)[i];
                pb[i] = ((const float4*)gb2)[i];
            }
        }
#pragma unroll 8
        for (int kk = 0; kk < 32; ++kk) {
            float4 a0 = *(const float4*)&As[kk][ty*8];
            float4 a1 = *(const float4*)&As[kk][ty*8+4];
            float4 b0 = *(const float4*)&Bs[kk][tx*8];
            float4 b1 = *(const float4*)&Bs[kk][tx*8+4];
            float av[8] = {a0.x,a0.y,a0.z,a0.w,a1.x,a1.y,a1.z,a1.w};
            float bv[8] = {b0.x,b0.y,b0.z,b0.w,b1.x,b1.y,b1.z,b1.w};
#pragma unroll
            for (int i = 0; i < 8; ++i)
#pragma unroll
                for (int j = 0; j < 8; ++j)
                    acc[i][j] = fmaf(av[i], bv[j], acc[i][j]);
        }
    }

#pragma unroll
    for (int i = 0; i < 8; ++i) {
        float* row = E + (size_t)(b * CCH + c0 + ty*8 + i) * CCH + d0 + tx*8;
        float4 v0 = {acc[i][0], acc[i][1], acc[i][2], acc[i][3]};
        float4 v1 = {acc[i][4], acc[i][5], acc[i][6], acc[i][7]};
        ((float4*)row)[0] = v0;
        ((float4*)row)[1] = v1;
    }
}

// ---------------------------------------------------------------------------
// K2: attention = softmax(max - energy) over d  ==  exp(min - e) / sum
// one block (256 thr) per row of 512. In-place on E.
// ---------------------------------------------------------------------------
__global__ __launch_bounds__(256)
void attn_softmax_kernel(float* __restrict__ E) {
    __shared__ float red[4];
    const int row = blockIdx.x;               // 0 .. B*C-1
    float* p = E + (size_t)row * CCH;
    const int t = threadIdx.x;
    float e0 = p[t];
    float e1 = p[t + 256];
    float m = fminf(e0, e1);
#pragma unroll
    for (int off = 32; off > 0; off >>= 1)
        m = fminf(m, __shfl_xor(m, off, 64));
    if ((t & 63) == 0) red[t >> 6] = m;
    __syncthreads();
    const float mAll = fminf(fminf(red[0], red[1]), fminf(red[2], red[3]));
    float x0 = __expf(mAll - e0);
    float x1 = __expf(mAll - e1);
    float s = x0 + x1;
#pragma unroll
    for (int off = 32; off > 0; off >>= 1)
        s += __shfl_xor(s, off, 64);
    __syncthreads();                          // everyone done reading red
    if ((t & 63) == 0) red[t >> 6] = s;
    __syncthreads();
    const float sAll = red[0] + red[1] + red[2] + red[3];
    const float r = 1.0f / sAll;
    p[t]       = x0 * r;
    p[t + 256] = x1 * r;
}

// ---------------------------------------------------------------------------
// K3: out[b] = att[b] (C x C) * kv[b] (C x N)   (NN GEMM, fp32)
// same tiling as K1; B-tile stages direct (no transpose needed).
// ---------------------------------------------------------------------------
__global__ __launch_bounds__(256)
void out_kernel(const float* __restrict__ att, const float* __restrict__ kv,
                float* __restrict__ out) {
    __shared__ float As[32][132];
    __shared__ float Bs[32][132];
    const int b  = blockIdx.z;
    const int c0 = blockIdx.y * 128;
    const int n0 = blockIdx.x * 128;
    const float* Abase = att + (size_t)b * CCH * CCH;
    const float* Bbase = kv  + (size_t)b * CCH * NTOK;
    const int tid   = threadIdx.x;
    const int tx    = tid & 15, ty = tid >> 4;
    const int lrow  = tid >> 1;          // A stage: tile row
    const int lk0   = (tid & 1) * 16;
    const int bkrow = tid >> 3;          // B stage: k row 0..31
    const int bseg  = (tid & 7) * 16;    // B stage: col seg

    const float* ga = Abase + (size_t)(c0 + lrow) * CCH + lk0;
    const float* gb = Bbase + (size_t)bkrow * NTOK + n0 + bseg;

    float acc[8][8];
#pragma unroll
    for (int i = 0; i < 8; ++i)
#pragma unroll
        for (int j = 0; j < 8; ++j) acc[i][j] = 0.f;

    float4 pa[4], pb[4];
#pragma unroll
    for (int i = 0; i < 4; ++i) {
        pa[i] = ((const float4*)ga)[i];
        pb[i] = ((const float4*)gb)[i];
    }

    for (int k0 = 0; k0 < CCH; k0 += 32) {
        __syncthreads();
#pragma unroll
        for (int i = 0; i < 4; ++i) {
            const int kb = lk0 + i * 4;
            As[kb+0][lrow] = pa[i].x; As[kb+1][lrow] = pa[i].y;
            As[kb+2][lrow] = pa[i].z; As[kb+3][lrow] = pa[i].w;
            *(float4*)&Bs[bkrow][bseg + i*4] = pb[i];
        }
        __syncthreads();
        if (k0 + 32 < CCH) {
            const float* ga2 = ga + (k0 + 32);
            const float* gb2 = gb + (size_t)(k0 + 32) * NTOK;
#pragma unroll
            for (int i = 0; i < 4; ++i) {
                pa[i] = ((const float4*)ga2)[i];
                pb[i] = ((const float4*)gb2)[i];
            }
        }
#pragma unroll 8
        for (int kk = 0; kk < 32; ++kk) {
            float4 a0 = *(const float4*)&As[kk][ty*8];
            float4 a1 = *(const float4*)&As[kk][ty*8+4];
            float4 b0 = *(const float4*)&Bs[kk][tx*8];
            float4 b1 = *(const float4*)&Bs[kk][tx*8+4];
            float av[8] = {a0.x,a0.y,a0.z,a0.w,a1.x,a1.y,a1.z,a1.w};
            float bv[8] = {b0.x,b0.y,b0.z,b0.w,b1.x,b1.y,b1.z,b1.w};
#pragma unroll
            for (int i = 0; i < 8; ++i)
#pragma unroll
                for (int j = 0; j < 8; ++j)
                    acc[i][j] = fmaf(av[i], bv[j], acc[i][j]);
        }
    }

#pragma unroll
    for (int i = 0; i < 8; ++i) {
        float* row = out + (size_t)(b * CCH + c0 + ty*8 + i) * NTOK + n0 + tx*8;
        float4 v0 = {acc[i][0], acc[i][1], acc[i][2], acc[i][3]};
        float4 v1 = {acc[i][4], acc[i][5], acc[i][6], acc[i][7]};
        ((float4*)row)[0] = v0;
        ((float4*)row)[1] = v1;
    }
}

// ---------------------------------------------------------------------------
// K4: final softmax over last axis W=64. One wave per 64-elem row, in place.
// ---------------------------------------------------------------------------
__global__ __launch_bounds__(256)
void softmax64_kernel(float* __restrict__ out) {
    const size_t wid = (size_t)blockIdx.x * 4 + (threadIdx.x >> 6);
    const int lane = threadIdx.x & 63;
    float* p = out + wid * 64;
    float x = p[lane];
    float m = x;
#pragma unroll
    for (int off = 32; off > 0; off >>= 1)
        m = fmaxf(m, __shfl_xor(m, off, 64));
    float e = __expf(x - m);
    float s = e;
#pragma unroll
    for (int off = 32; off > 0; off >>= 1)
        s += __shfl_xor(s, off, 64);
    p[lane] = e / s;
}

// ---------------------------------------------------------------------------
extern "C" void kernel_launch(void* const* d_in, const int* in_sizes, int n_in,
                              void* d_out, int out_size, void* d_ws, size_t ws_size,
                              hipStream_t stream) {
    const float* x_training = (const float*)d_in[0];  // kv
    const float* x_pre      = (const float*)d_in[1];  // q
    float* out = (float*)d_out;
    float* E   = (float*)d_ws;   // B*C*C fp32 = 16 MiB scratch (energy->attention in place)

    energy_kernel<<<dim3(CCH/128, CCH/128, NBATCH), dim3(256), 0, stream>>>(x_pre, x_training, E);
    attn_softmax_kernel<<<dim3(NBATCH * CCH), dim3(256), 0, stream>>>(E);
    out_kernel<<<dim3(NTOK/128, CCH/128, NBATCH), dim3(256), 0, stream>>>(E, x_training, out);
    softmax64_kernel<<<dim3(NBATCH * CCH * 64 / 4), dim3(256), 0, stream>>>(out);
}

// Round 2
// 456.376 us; speedup vs baseline: 2.6095x; 2.6095x over previous
//
#include <hip/hip_runtime.h>
#include <hip/hip_bf16.h>
#include <math.h>

// B=16, C=512, H=W=64, N=4096
#define CCH  512
#define NTOK 4096
#define NB   16
#define KSPL 2048          // split-K half length for energy GEMM
#define LDA  40            // LDS row stride in shorts (80 B: 16B-aligned, breaks pow2 banks)

typedef __attribute__((ext_vector_type(8))) short s8v;   // 8 bf16 (4 VGPRs)
typedef __attribute__((ext_vector_type(4))) float f4v;   // 4 fp32 acc
typedef unsigned short u16;

// fp32 -> (hi, lo) bf16 pair, RNE both. x ~= hi + lo with rel err ~2^-16.
__device__ __forceinline__ void split2(float2 f, ushort2& hi, ushort2& lo) {
    __hip_bfloat162 h = __float22bfloat162_rn(f);
    float2 hf = __bfloat1622float2(h);
    __hip_bfloat162 l = __float22bfloat162_rn(make_float2(f.x - hf.x, f.y - hf.y));
    hi = *reinterpret_cast<ushort2*>(&h);
    lo = *reinterpret_cast<ushort2*>(&l);
}
__device__ __forceinline__ u16 bfrne(float x) {
    __hip_bfloat16 h = __float2bfloat16(x);
    return *reinterpret_cast<u16*>(&h);
}

// ---------------------------------------------------------------------------
// K1: E[s][b][c][d] partial = sum_{k in split s} q[b,c,k] * kv[b,d,k]
// 128x128 tile, BK=32, 16x16x32 bf16 MFMA, split-bf16 3-product. grid (4,4,32)
// ---------------------------------------------------------------------------
__global__ __launch_bounds__(256, 2)
void energy_mfma(const float* __restrict__ q, const float* __restrict__ kv,
                 float* __restrict__ E) {
    __shared__ short Ah[128 * LDA], Al[128 * LDA], Bh[128 * LDA], Bl[128 * LDA];
    const int b  = blockIdx.z >> 1;
    const int s  = blockIdx.z & 1;
    const int c0 = blockIdx.y * 128, d0 = blockIdx.x * 128;
    const int tid  = threadIdx.x;
    const int lane = tid & 63, wave = tid >> 6;
    const int wm = wave & 1, wn = wave >> 1;
    const int l15 = lane & 15, quad = lane >> 4;

    const int srow = tid >> 1;          // staged tile row 0..127
    const int skq  = (tid & 1) * 16;    // k offset 0/16
    const float* ga = q  + ((size_t)(b * CCH + c0 + srow)) * NTOK + s * KSPL + skq;
    const float* gb = kv + ((size_t)(b * CCH + d0 + srow)) * NTOK + s * KSPL + skq;

    f4v acc[4][4];
#pragma unroll
    for (int i = 0; i < 4; ++i)
#pragma unroll
        for (int j = 0; j < 4; ++j) acc[i][j] = (f4v)0.f;

    float4 pa[4], pb[4];
#pragma unroll
    for (int i = 0; i < 4; ++i) {
        pa[i] = ((const float4*)ga)[i];
        pb[i] = ((const float4*)gb)[i];
    }

    for (int kc = 0; kc < KSPL; kc += 32) {
        __syncthreads();
#pragma unroll
        for (int i = 0; i < 4; ++i) {
            ushort2 h0, l0, h1, l1;
            split2(make_float2(pa[i].x, pa[i].y), h0, l0);
            split2(make_float2(pa[i].z, pa[i].w), h1, l1);
            *(ushort4*)&Ah[srow * LDA + skq + i * 4] = make_ushort4(h0.x, h0.y, h1.x, h1.y);
            *(ushort4*)&Al[srow * LDA + skq + i * 4] = make_ushort4(l0.x, l0.y, l1.x, l1.y);
            split2(make_float2(pb[i].x, pb[i].y), h0, l0);
            split2(make_float2(pb[i].z, pb[i].w), h1, l1);
            *(ushort4*)&Bh[srow * LDA + skq + i * 4] = make_ushort4(h0.x, h0.y, h1.x, h1.y);
            *(ushort4*)&Bl[srow * LDA + skq + i * 4] = make_ushort4(l0.x, l0.y, l1.x, l1.y);
        }
        __syncthreads();
        if (kc + 32 < KSPL) {
            const float* ga2 = ga + kc + 32;
            const float* gb2 = gb + kc + 32;
#pragma unroll
            for (int i = 0; i < 4; ++i) {
                pa[i] = ((const float4*)ga2)[i];
                pb[i] = ((const float4*)gb2)[i];
            }
        }
        const int koff = quad * 8;
        const int abase = (wm * 64 + l15) * LDA + koff;
        const int bbase = (wn * 64 + l15) * LDA + koff;
        s8v a_h[4], a_l[4];
#pragma unroll
        for (int i = 0; i < 4; ++i) {
            a_h[i] = *(const s8v*)&Ah[abase + i * 16 * LDA];
            a_l[i] = *(const s8v*)&Al[abase + i * 16 * LDA];
        }
#pragma unroll
        for (int j = 0; j < 4; ++j) {
            s8v b_h = *(const s8v*)&Bh[bbase + j * 16 * LDA];
            s8v b_l = *(const s8v*)&Bl[bbase + j * 16 * LDA];
#pragma unroll
            for (int i = 0; i < 4; ++i) {
                acc[i][j] = __builtin_amdgcn_mfma_f32_16x16x32_bf16(a_h[i], b_h, acc[i][j], 0, 0, 0);
                acc[i][j] = __builtin_amdgcn_mfma_f32_16x16x32_bf16(a_h[i], b_l, acc[i][j], 0, 0, 0);
                acc[i][j] = __builtin_amdgcn_mfma_f32_16x16x32_bf16(a_l[i], b_h, acc[i][j], 0, 0, 0);
            }
        }
    }

    float* Eb = E + ((size_t)(s * NB + b)) * CCH * CCH;
#pragma unroll
    for (int i = 0; i < 4; ++i)
#pragma unroll
        for (int r = 0; r < 4; ++r) {
            const int row = c0 + wm * 64 + i * 16 + quad * 4 + r;
#pragma unroll
            for (int j = 0; j < 4; ++j)
                Eb[(size_t)row * CCH + d0 + wn * 64 + j * 16 + l15] = acc[i][j][r];
        }
}

// ---------------------------------------------------------------------------
// K2: att = softmax(min - e) over d, e = E0 + E1. Emits att as bf16 hi/lo.
// ---------------------------------------------------------------------------
__global__ __launch_bounds__(256)
void attn_softmax(const float* __restrict__ E0, const float* __restrict__ E1,
                  u16* __restrict__ ah, u16* __restrict__ al) {
    __shared__ float red[4];
    const size_t base = (size_t)blockIdx.x * CCH;
    const int t = threadIdx.x;
    float e0 = E0[base + t] + E1[base + t];
    float e1 = E0[base + t + 256] + E1[base + t + 256];
    float m = fminf(e0, e1);
#pragma unroll
    for (int off = 32; off > 0; off >>= 1) m = fminf(m, __shfl_xor(m, off, 64));
    if ((t & 63) == 0) red[t >> 6] = m;
    __syncthreads();
    const float mAll = fminf(fminf(red[0], red[1]), fminf(red[2], red[3]));
    float x0 = __expf(mAll - e0);
    float x1 = __expf(mAll - e1);
    float sum = x0 + x1;
#pragma unroll
    for (int off = 32; off > 0; off >>= 1) sum += __shfl_xor(sum, off, 64);
    __syncthreads();
    if ((t & 63) == 0) red[t >> 6] = sum;
    __syncthreads();
    const float inv = 1.0f / (red[0] + red[1] + red[2] + red[3]);
    float a0 = x0 * inv, a1 = x1 * inv;
    __hip_bfloat16 h0 = __float2bfloat16(a0);
    __hip_bfloat16 h1 = __float2bfloat16(a1);
    ah[base + t]       = *reinterpret_cast<u16*>(&h0);
    ah[base + t + 256] = *reinterpret_cast<u16*>(&h1);
    __hip_bfloat16 g0 = __float2bfloat16(a0 - __bfloat162float(h0));
    __hip_bfloat16 g1 = __float2bfloat16(a1 - __bfloat162float(h1));
    al[base + t]       = *reinterpret_cast<u16*>(&g0);
    al[base + t + 256] = *reinterpret_cast<u16*>(&g1);
}

// ---------------------------------------------------------------------------
// K3: out = att (C x C) * kv (C x N), att split (hi,lo) x kv bf16 (2 products),
// fused final softmax over W=64 in the epilogue. grid (32,4,16).
// ---------------------------------------------------------------------------
__global__ __launch_bounds__(256, 2)
void out_mfma(const u16* __restrict__ atth, const u16* __restrict__ attl,
              const float* __restrict__ kv, float* __restrict__ out) {
    __shared__ short Ah[128 * LDA], Al[128 * LDA], Bs[128 * LDA];
    const int b  = blockIdx.z;
    const int c0 = blockIdx.y * 128;
    const int n0 = blockIdx.x * 128;
    const int tid  = threadIdx.x;
    const int lane = tid & 63, wave = tid >> 6;
    const int wm = wave & 1, wn = wave >> 1;
    const int l15 = lane & 15, quad = lane >> 4;

    // A staging map (rows of att, k contiguous)
    const int arow = tid >> 1, akq = (tid & 1) * 16;
    const u16* gah = atth + ((size_t)(b * CCH + c0 + arow)) * CCH + akq;
    const u16* gal = attl + ((size_t)(b * CCH + c0 + arow)) * CCH + akq;
    // B staging map (transpose: 128 n-lanes x 16 k each)
    const int bn = tid & 127, bkg = (tid >> 7) * 16;
    const float* gb = kv + (size_t)b * CCH * NTOK + n0 + bn;

    f4v acc[4][4];
#pragma unroll
    for (int i = 0; i < 4; ++i)
#pragma unroll
        for (int j = 0; j < 4; ++j) acc[i][j] = (f4v)0.f;

    ushort4 pah[4], pal[4];
    float pbf[16];
#pragma unroll
    for (int i = 0; i < 4; ++i) {
        pah[i] = *(const ushort4*)(gah + i * 4);
        pal[i] = *(const ushort4*)(gal + i * 4);
    }
#pragma unroll
    for (int t = 0; t < 16; ++t) pbf[t] = gb[(size_t)(bkg + t) * NTOK];

    for (int kc = 0; kc < CCH; kc += 32) {
        __syncthreads();
#pragma unroll
        for (int i = 0; i < 4; ++i) {
            *(ushort4*)&Ah[arow * LDA + akq + i * 4] = pah[i];
            *(ushort4*)&Al[arow * LDA + akq + i * 4] = pal[i];
        }
#pragma unroll
        for (int p = 0; p < 4; ++p) {
            ushort4 v = make_ushort4(bfrne(pbf[p * 4 + 0]), bfrne(pbf[p * 4 + 1]),
                                     bfrne(pbf[p * 4 + 2]), bfrne(pbf[p * 4 + 3]));
            *(ushort4*)&Bs[bn * LDA + bkg + p * 4] = v;
        }
        __syncthreads();
        if (kc + 32 < CCH) {
#pragma unroll
            for (int i = 0; i < 4; ++i) {
                pah[i] = *(const ushort4*)(gah + kc + 32 + i * 4);
                pal[i] = *(const ushort4*)(gal + kc + 32 + i * 4);
            }
#pragma unroll
            for (int t = 0; t < 16; ++t) pbf[t] = gb[(size_t)(kc + 32 + bkg + t) * NTOK];
        }
        const int koff = quad * 8;
        const int abase = (wm * 64 + l15) * LDA + koff;
        const int bbase = (wn * 64 + l15) * LDA + koff;
        s8v a_h[4], a_l[4];
#pragma unroll
        for (int i = 0; i < 4; ++i) {
            a_h[i] = *(const s8v*)&Ah[abase + i * 16 * LDA];
            a_l[i] = *(const s8v*)&Al[abase + i * 16 * LDA];
        }
#pragma unroll
        for (int j = 0; j < 4; ++j) {
            s8v bb = *(const s8v*)&Bs[bbase + j * 16 * LDA];
#pragma unroll
            for (int i = 0; i < 4; ++i) {
                acc[i][j] = __builtin_amdgcn_mfma_f32_16x16x32_bf16(a_h[i], bb, acc[i][j], 0, 0, 0);
                acc[i][j] = __builtin_amdgcn_mfma_f32_16x16x32_bf16(a_l[i], bb, acc[i][j], 0, 0, 0);
            }
        }
    }

    // epilogue: softmax over W=64 (cols j*16+l15 within this wave's 64-col group)
#pragma unroll
    for (int i = 0; i < 4; ++i) {
#pragma unroll
        for (int r = 0; r < 4; ++r) {
            float v0 = acc[i][0][r], v1 = acc[i][1][r], v2 = acc[i][2][r], v3 = acc[i][3][r];
            float m = fmaxf(fmaxf(v0, v1), fmaxf(v2, v3));
#pragma unroll
            for (int off = 8; off > 0; off >>= 1) m = fmaxf(m, __shfl_xor(m, off, 16));
            float e0 = __expf(v0 - m), e1 = __expf(v1 - m), e2 = __expf(v2 - m), e3 = __expf(v3 - m);
            float sum = e0 + e1 + e2 + e3;
#pragma unroll
            for (int off = 8; off > 0; off >>= 1) sum += __shfl_xor(sum, off, 16);
            const float inv = 1.0f / sum;
            const int row = c0 + wm * 64 + i * 16 + quad * 4 + r;
            float* op = out + ((size_t)(b * CCH + row)) * NTOK + n0 + wn * 64 + l15;
            op[0]  = e0 * inv;
            op[16] = e1 * inv;
            op[32] = e2 * inv;
            op[48] = e3 * inv;
        }
    }
}

// ---------------------------------------------------------------------------
extern "C" void kernel_launch(void* const* d_in, const int* in_sizes, int n_in,
                              void* d_out, int out_size, void* d_ws, size_t ws_size,
                              hipStream_t stream) {
    const float* x_training = (const float*)d_in[0];  // kv
    const float* x_pre      = (const float*)d_in[1];  // q
    float* out = (float*)d_out;
    const size_t ES = (size_t)NB * CCH * CCH;         // 4.19M elems
    float* E0 = (float*)d_ws;                          // 16 MiB
    float* E1 = E0 + ES;                               // 16 MiB
    u16* ath = (u16*)(E1 + ES);                        // 8 MiB
    u16* atl = ath + ES;                               // 8 MiB

    energy_mfma<<<dim3(4, 4, 32), 256, 0, stream>>>(x_pre, x_training, E0);
    attn_softmax<<<dim3(NB * CCH), 256, 0, stream>>>(E0, E1, ath, atl);
    out_mfma<<<dim3(NTOK / 128, CCH / 128, NB), 256, 0, stream>>>(ath, atl, x_training, out);
}